// Round 1
// 661.187 us; speedup vs baseline: 1.1739x; 1.1739x over previous
//
#include <hip/hip_runtime.h>

#define S_LEN 2048
#define BATCH 64
#define DMODEL 512
#define NHEAD 8
#define HDIM 64
#define LN_EPS_F 1e-5f
#define QSCALE 0.125f  // 1/sqrt(64)

// ---------------------------------------------------------------------------
// K1: q[b,d] = (src[last_b, b, :] @ Wq^T + bq)*scale for d in [y*256,(y+1)*256)
//     then qk[b,h,:] for heads h in [y*4, y*4+4)  (those only need this q range)
// grid: (B, 2), 256 threads
// ---------------------------------------------------------------------------
__global__ void __launch_bounds__(256) k_q_qk(
    const float* __restrict__ src, const int* __restrict__ seqlen,
    const float* __restrict__ w_in, const float* __restrict__ b_in,
    float* __restrict__ qk)
{
    __shared__ float xl[DMODEL];
    __shared__ float ql[256];
    const int b = blockIdx.x;
    const int y = blockIdx.y;
    const int t = threadIdx.x;
    const int last = seqlen[b] - 1;
    const float* xrow = src + ((size_t)last * BATCH + b) * DMODEL;
    for (int i = t; i < DMODEL; i += 256) xl[i] = xrow[i];
    __syncthreads();
    {
        const int d = y * 256 + t;
        const float* wr = w_in + (size_t)d * DMODEL;
        float acc = b_in[d];
        for (int i = 0; i < DMODEL; i += 4) {
            const float4 r = *reinterpret_cast<const float4*>(wr + i);
            acc += r.x * xl[i] + r.y * xl[i + 1] + r.z * xl[i + 2] + r.w * xl[i + 3];
        }
        ql[t] = acc * QSCALE;
    }
    __syncthreads();
    // qk[b][h][dp] = sum_j Wk[h*64+j][dp] * q[h*64+j]  (bk drops out of softmax)
#pragma unroll
    for (int r = 0; r < 8; r++) {
        const int hl = r >> 1;                 // local head 0..3
        const int dp = (r & 1) * 256 + t;
        const int h = y * 4 + hl;
        float acc = 0.f;
#pragma unroll 16
        for (int j = 0; j < HDIM; j++)
            acc += w_in[((size_t)(DMODEL + h * HDIM + j)) * DMODEL + dp] * ql[hl * HDIM + j];
        qk[((size_t)b * NHEAD + h) * DMODEL + dp] = acc;
    }
}

// ---------------------------------------------------------------------------
// K2: scores[b,h,s] = qk[b,h,:] . src[s,b,:]
// grid: (B, S/32), 256 threads = 4 waves, each wave does 8 s-values.
// 64 accumulators/lane (8 s x 8 heads), ONE packed butterfly fold (63 shfl)
// instead of 384 shfl; every lane ends with one score -> coalesced store.
// ---------------------------------------------------------------------------
__global__ void __launch_bounds__(256) k_scores(
    const float* __restrict__ src, const float* __restrict__ qk,
    float* __restrict__ scores)
{
    const int b = blockIdx.x;
    const int sb = blockIdx.y;
    const int t = threadIdx.x;
    const int wave = t >> 6, lane = t & 63;

    float qr[NHEAD][8];
    const float* qb = qk + (size_t)b * NHEAD * DMODEL + lane * 8;
#pragma unroll
    for (int h = 0; h < NHEAD; h++) {
        const float4 a = *reinterpret_cast<const float4*>(qb + h * DMODEL);
        const float4 c = *reinterpret_cast<const float4*>(qb + h * DMODEL + 4);
        qr[h][0] = a.x; qr[h][1] = a.y; qr[h][2] = a.z; qr[h][3] = a.w;
        qr[h][4] = c.x; qr[h][5] = c.y; qr[h][6] = c.z; qr[h][7] = c.w;
    }
    const int sbase = sb * 32 + wave * 8;
    float acc[64];  // acc[h*8+i] = partial score for (head h, s = sbase+i)
#pragma unroll
    for (int j = 0; j < 64; j++) acc[j] = 0.f;
#pragma unroll
    for (int i = 0; i < 8; i++) {
        const float* xrow = src + ((size_t)(sbase + i) * BATCH + b) * DMODEL + lane * 8;
        const float4 xa = *reinterpret_cast<const float4*>(xrow);
        const float4 xc = *reinterpret_cast<const float4*>(xrow + 4);
        float xf[8];
        xf[0] = xa.x; xf[1] = xa.y; xf[2] = xa.z; xf[3] = xa.w;
        xf[4] = xc.x; xf[5] = xc.y; xf[6] = xc.z; xf[7] = xc.w;
#pragma unroll
        for (int h = 0; h < NHEAD; h++) {
            float a = acc[h * 8 + i];
#pragma unroll
            for (int j = 0; j < 8; j++) a += qr[h][j] * xf[j];
            acc[h * 8 + i] = a;
        }
    }
    // packed butterfly fold: after stage k (mask m), lane keeps the half of its
    // values whose index-bit matches its own lane bit m. Final: lane l holds the
    // full sum for j = l, i.e. head = l>>3, s-offset = l&7.
#pragma unroll
    for (int st = 0; st < 6; st++) {
        const int m = 32 >> st;
        const int nh = 32 >> st;   // active count / 2
        const bool hi = (lane & m) != 0;
#pragma unroll
        for (int j = 0; j < nh; j++) {
            const float keep = hi ? acc[j + nh] : acc[j];
            const float give = hi ? acc[j] : acc[j + nh];
            acc[j] = keep + __shfl_xor(give, m, 64);
        }
    }
    scores[((size_t)b * NHEAD + (lane >> 3)) * S_LEN + sbase + (lane & 7)] = acc[0];
}

// ---------------------------------------------------------------------------
// K3: softmax over s for each (b,h). grid: B*H blocks, 256 threads.
// Wave-shuffle reduction + 4-entry LDS combine (2 syncthreads total).
// ---------------------------------------------------------------------------
__global__ void __launch_bounds__(256) k_softmax(float* __restrict__ scores)
{
    const int bh = blockIdx.x;
    const int t = threadIdx.x;
    const int wave = t >> 6, lane = t & 63;
    float* p = scores + (size_t)bh * S_LEN;
    float v[8];
    float m = -1e30f;
#pragma unroll
    for (int k = 0; k < 8; k++) { v[k] = p[t + k * 256]; m = fmaxf(m, v[k]); }
#pragma unroll
    for (int mk = 32; mk; mk >>= 1) m = fmaxf(m, __shfl_xor(m, mk, 64));
    __shared__ float redm[4], reds[4];
    if (lane == 0) redm[wave] = m;
    __syncthreads();
    m = fmaxf(fmaxf(redm[0], redm[1]), fmaxf(redm[2], redm[3]));
    float s = 0.f;
#pragma unroll
    for (int k = 0; k < 8; k++) { v[k] = __expf(v[k] - m); s += v[k]; }
#pragma unroll
    for (int mk = 32; mk; mk >>= 1) s += __shfl_xor(s, mk, 64);
    if (lane == 0) reds[wave] = s;
    __syncthreads();
    const float inv = 1.0f / (reds[0] + reds[1] + reds[2] + reds[3]);
#pragma unroll
    for (int k = 0; k < 8; k++) p[t + k * 256] = v[k] * inv;
}

// ---------------------------------------------------------------------------
// K4: xbar partials: xpart[c][b][h][d] = sum_{s in chunk c} attn[b,h,s]*src[s,b,d]
// grid: (B, 8 chunks of 256 s), 256 threads; thread owns d=2t,2t+1.
// attn tile staged TRANSPOSED (al[s][h]) so inner loop is 2 broadcast
// ds_read_b128 instead of 8 ds_read_b32.
// ---------------------------------------------------------------------------
__global__ void __launch_bounds__(256) k_xbar(
    const float* __restrict__ src, const float* __restrict__ attn,
    float* __restrict__ xpart)
{
    __shared__ float al[256][8];  // 8 KB, rows 32B-aligned for float4 reads
    const int b = blockIdx.x;
    const int c = blockIdx.y;
    const int t = threadIdx.x;
    const int s0 = c * 256;
    {
        float v[8];
#pragma unroll
        for (int h = 0; h < NHEAD; h++)
            v[h] = attn[((size_t)b * NHEAD + h) * S_LEN + s0 + t];
        *reinterpret_cast<float4*>(&al[t][0]) = make_float4(v[0], v[1], v[2], v[3]);
        *reinterpret_cast<float4*>(&al[t][4]) = make_float4(v[4], v[5], v[6], v[7]);
    }
    __syncthreads();
    float acc0[NHEAD] = {0.f, 0.f, 0.f, 0.f, 0.f, 0.f, 0.f, 0.f};
    float acc1[NHEAD] = {0.f, 0.f, 0.f, 0.f, 0.f, 0.f, 0.f, 0.f};
    const float* base = src + (size_t)s0 * BATCH * DMODEL + (size_t)b * DMODEL + 2 * t;
#pragma unroll 4
    for (int i = 0; i < 256; i++) {
        const float2 xv = *reinterpret_cast<const float2*>(base + (size_t)i * BATCH * DMODEL);
        const float4 a0 = *reinterpret_cast<const float4*>(&al[i][0]);
        const float4 a1 = *reinterpret_cast<const float4*>(&al[i][4]);
        acc0[0] += a0.x * xv.x; acc1[0] += a0.x * xv.y;
        acc0[1] += a0.y * xv.x; acc1[1] += a0.y * xv.y;
        acc0[2] += a0.z * xv.x; acc1[2] += a0.z * xv.y;
        acc0[3] += a0.w * xv.x; acc1[3] += a0.w * xv.y;
        acc0[4] += a1.x * xv.x; acc1[4] += a1.x * xv.y;
        acc0[5] += a1.y * xv.x; acc1[5] += a1.y * xv.y;
        acc0[6] += a1.z * xv.x; acc1[6] += a1.z * xv.y;
        acc0[7] += a1.w * xv.x; acc1[7] += a1.w * xv.y;
    }
#pragma unroll
    for (int h = 0; h < NHEAD; h++) {
        const size_t idx = (((size_t)c * BATCH + b) * NHEAD + h) * DMODEL + 2 * t;
        *reinterpret_cast<float2*>(xpart + idx) = make_float2(acc0[h], acc1[h]);
    }
}

// ---------------------------------------------------------------------------
// K5a: reduce partials for 4 heads -> ctx[e] = Wv[e,:] . xbar[h(e),:] + bv[e]
// grid: (B, 2), 256 threads; block y covers e in [y*256, y*256+256) = heads y*4..y*4+3
// ---------------------------------------------------------------------------
__global__ void __launch_bounds__(256) k_ctx(
    const float* __restrict__ xpart, const float* __restrict__ w_in,
    const float* __restrict__ b_in, float* __restrict__ ctx)
{
    __shared__ float xb[4 * DMODEL];  // 8 KB: xbar for this block's 4 heads
    const int b = blockIdx.x;
    const int y = blockIdx.y;
    const int t = threadIdx.x;
    for (int i = t; i < 4 * DMODEL; i += 256) {
        float a = 0.f;
#pragma unroll
        for (int c = 0; c < 8; c++)
            a += xpart[((size_t)c * BATCH + b) * (NHEAD * DMODEL) + y * 4 * DMODEL + i];
        xb[i] = a;
    }
    __syncthreads();
    const int e = y * 256 + t;
    const int hl = t >> 6;  // local head index within this block
    const float* wr = w_in + ((size_t)(2 * DMODEL + e)) * DMODEL;
    const float* xr = &xb[hl * DMODEL];
    float acc = b_in[2 * DMODEL + e];
    for (int d = 0; d < DMODEL; d += 4) {
        const float4 r = *reinterpret_cast<const float4*>(wr + d);
        acc += r.x * xr[d] + r.y * xr[d + 1] + r.z * xr[d + 2] + r.w * xr[d + 3];
    }
    ctx[(size_t)b * DMODEL + e] = acc;
}

// ---------------------------------------------------------------------------
// K5b: attn_out = ctx . Wout^T + bout. grid: (B, 2), 256 threads, 1 output each.
// ---------------------------------------------------------------------------
__global__ void __launch_bounds__(256) k_outproj(
    const float* __restrict__ ctx, const float* __restrict__ w_out,
    const float* __restrict__ b_out, float* __restrict__ attn_out)
{
    __shared__ float cl[DMODEL];
    const int b = blockIdx.x;
    const int y = blockIdx.y;
    const int t = threadIdx.x;
    for (int i = t; i < DMODEL; i += 256) cl[i] = ctx[(size_t)b * DMODEL + i];
    __syncthreads();
    const int o = y * 256 + t;
    const float* wr = w_out + (size_t)o * DMODEL;
    float acc = b_out[o];
    for (int e = 0; e < DMODEL; e += 4) {
        const float4 r = *reinterpret_cast<const float4*>(wr + e);
        acc += r.x * cl[e] + r.y * cl[e + 1] + r.z * cl[e + 2] + r.w * cl[e + 3];
    }
    attn_out[(size_t)b * DMODEL + o] = acc;
}

// ---------------------------------------------------------------------------
// K6: out[s,b,:] = LayerNorm(src[s,b,:] + attn_out[b,:]) * g + beta
// WAVE-PER-ROW: no LDS, no __syncthreads. 8 elems/lane, 12-shuffle butterfly.
// grid: S*B/4 blocks x 256 threads (4 rows/block).
// ---------------------------------------------------------------------------
__global__ void __launch_bounds__(256) k_ln(
    const float* __restrict__ src, const float* __restrict__ attn_out,
    const float* __restrict__ g, const float* __restrict__ beta,
    float* __restrict__ out)
{
    const int t = threadIdx.x;
    const int wave = t >> 6, lane = t & 63;
    const int row = blockIdx.x * 4 + wave;  // s*BATCH + b
    const int b = row & (BATCH - 1);
    const int d0 = lane * 8;
    const float* xp = src + (size_t)row * DMODEL + d0;
    const float4 xa = *reinterpret_cast<const float4*>(xp);
    const float4 xc = *reinterpret_cast<const float4*>(xp + 4);
    const float* ap = attn_out + (size_t)b * DMODEL + d0;
    const float4 aa = *reinterpret_cast<const float4*>(ap);
    const float4 ac = *reinterpret_cast<const float4*>(ap + 4);
    float x[8];
    x[0] = xa.x + aa.x; x[1] = xa.y + aa.y; x[2] = xa.z + aa.z; x[3] = xa.w + aa.w;
    x[4] = xc.x + ac.x; x[5] = xc.y + ac.y; x[6] = xc.z + ac.z; x[7] = xc.w + ac.w;
    float s1 = 0.f, s2 = 0.f;
#pragma unroll
    for (int j = 0; j < 8; j++) { s1 += x[j]; s2 += x[j] * x[j]; }
#pragma unroll
    for (int m = 32; m; m >>= 1) {
        s1 += __shfl_xor(s1, m, 64);
        s2 += __shfl_xor(s2, m, 64);
    }
    const float mu = s1 * (1.0f / DMODEL);
    const float var = s2 * (1.0f / DMODEL) - mu * mu;
    const float inv = rsqrtf(var + LN_EPS_F);
    const float4 ga = *reinterpret_cast<const float4*>(g + d0);
    const float4 gc = *reinterpret_cast<const float4*>(g + d0 + 4);
    const float4 ba = *reinterpret_cast<const float4*>(beta + d0);
    const float4 bc = *reinterpret_cast<const float4*>(beta + d0 + 4);
    float4 y0, y1;
    y0.x = (x[0] - mu) * inv * ga.x + ba.x;
    y0.y = (x[1] - mu) * inv * ga.y + ba.y;
    y0.z = (x[2] - mu) * inv * ga.z + ba.z;
    y0.w = (x[3] - mu) * inv * ga.w + ba.w;
    y1.x = (x[4] - mu) * inv * gc.x + bc.x;
    y1.y = (x[5] - mu) * inv * gc.y + bc.y;
    y1.z = (x[6] - mu) * inv * gc.z + bc.z;
    y1.w = (x[7] - mu) * inv * gc.w + bc.w;
    float* op = out + (size_t)row * DMODEL + d0;
    *reinterpret_cast<float4*>(op) = y0;
    *reinterpret_cast<float4*>(op + 4) = y1;
}

extern "C" void kernel_launch(void* const* d_in, const int* in_sizes, int n_in,
                              void* d_out, int out_size, void* d_ws, size_t ws_size,
                              hipStream_t stream)
{
    const float* src   = (const float*)d_in[0];
    const int*   slen  = (const int*)d_in[1];
    const float* w_in  = (const float*)d_in[2];
    const float* b_in  = (const float*)d_in[3];
    const float* w_out = (const float*)d_in[4];
    const float* b_out = (const float*)d_in[5];
    const float* g     = (const float*)d_in[6];
    const float* beta  = (const float*)d_in[7];
    float* out = (float*)d_out;

    char* ws = (char*)d_ws;
    float* qk       = (float*)(ws);                                  // B*H*D   = 1 MB
    float* scores   = (float*)(ws + (1u << 20));                     // B*H*S   = 4 MB
    float* xpart    = (float*)(ws + 5u * (1u << 20));                // 8*B*H*D = 8 MB
    float* attn_out = (float*)(ws + 13u * (1u << 20));               // B*D     = 128 KB
    float* ctxbuf   = (float*)(ws + 13u * (1u << 20) + (1u << 17));  // B*D     = 128 KB

    k_q_qk<<<dim3(BATCH, 2), 256, 0, stream>>>(src, slen, w_in, b_in, qk);
    k_scores<<<dim3(BATCH, S_LEN / 32), 256, 0, stream>>>(src, qk, scores);
    k_softmax<<<BATCH * NHEAD, 256, 0, stream>>>(scores);
    k_xbar<<<dim3(BATCH, 8), 256, 0, stream>>>(src, scores, xpart);
    k_ctx<<<dim3(BATCH, 2), 256, 0, stream>>>(xpart, w_in, b_in, ctxbuf);
    k_outproj<<<dim3(BATCH, 2), 256, 0, stream>>>(ctxbuf, w_out, b_out, attn_out);
    k_ln<<<S_LEN * BATCH / 4, 256, 0, stream>>>(src, attn_out, g, beta, out);
}